// Round 1
// baseline (7261.497 us; speedup 1.0000x reference)
//
#include <hip/hip_runtime.h>

// EncoderLSTMContinuous: persistent per-row-tile scan kernel.
// Each WG owns MT=32 rows, keeps state/activations in LDS for all 32 steps,
// streams fp16 weights (pre-transposed to [N][K]) from L2.
// Round-1 design: L2-weight-stream bound (~27.9 GB @ ~34.5 TB/s => ~810us floor).

typedef _Float16 half_t;
typedef _Float16 half8 __attribute__((ext_vector_type(8)));
typedef _Float16 half4v __attribute__((ext_vector_type(4)));
typedef float float4_ __attribute__((ext_vector_type(4)));

#define UNITS 512
#define IN_DIM 1024
#define NROWS 8192
#define DEPTH 32
#define ZK 256
#define MT 32
#define PITCH (UNITS + 8)    // 520 halves; row stride 1040B -> bank step 4 (conflict-friendly)
#define XPITCH (IN_DIM + 8)  // 1032 halves

__device__ inline float4_ mfma16(half8 a, half8 b, float4_ c) {
  // A[m=lane&15][k=(lane>>4)*8+j], B[k=(lane>>4)*8+j][n=lane&15],
  // C/D: row=(lane>>4)*4+reg, col=lane&15  (m89/m120-verified layouts)
  return __builtin_amdgcn_mfma_f32_16x16x32_f16(a, b, c, 0, 0, 0);
}
__device__ inline float fast_sigmoid(float x) {
  return __builtin_amdgcn_rcpf(1.0f + __builtin_amdgcn_exp2f(-1.4426950408889634f * x));
}
__device__ inline float fast_tanh(float x) {
  return 2.0f * __builtin_amdgcn_rcpf(1.0f + __builtin_amdgcn_exp2f(-2.8853900817779268f * x)) - 1.0f;
}

// C[MT x (NB*16)] = A_lds[MT x K] * B^T  (B stored [N][K] row-major, fp16)
// Wave handles NB 16-col blocks; bbase already includes (colbase + c16)*K + q*8.
// k0 and k0+32 b-frags pair up to consume full 128B lines.
template<int NB, int K, int AP, class OffF>
__device__ inline void stage_gemm(const half_t* __restrict__ bbase, OffF off,
                                  const half_t* __restrict__ A, int q, int c16,
                                  float4_ (&acc)[NB][2]) {
#pragma unroll
  for (int nb = 0; nb < NB; ++nb) {
    acc[nb][0] = {0.f, 0.f, 0.f, 0.f};
    acc[nb][1] = {0.f, 0.f, 0.f, 0.f};
  }
  for (int k0 = 0; k0 < K; k0 += 64) {
    const half_t* ap = A + c16 * AP + k0 + q * 8;
    half8 a00 = *(const half8*)(ap);
    half8 a01 = *(const half8*)(ap + 32);
    half8 a10 = *(const half8*)(ap + 16 * AP);
    half8 a11 = *(const half8*)(ap + 16 * AP + 32);
#pragma unroll
    for (int nb = 0; nb < NB; ++nb) {
      const half_t* bp = bbase + off(nb) + k0;
      half8 b0 = *(const half8*)(bp);
      half8 b1 = *(const half8*)(bp + 32);
      acc[nb][0] = mfma16(a00, b0, acc[nb][0]);
      acc[nb][0] = mfma16(a01, b1, acc[nb][0]);
      acc[nb][1] = mfma16(a10, b0, acc[nb][1]);
      acc[nb][1] = mfma16(a11, b1, acc[nb][1]);
    }
  }
}

// ---- prep: fp32 [R][C] -> fp16 [C][R] tiled transpose-convert
__global__ void transpose_convert(const float* __restrict__ in, half_t* __restrict__ out,
                                  int R, int C) {
  __shared__ float tile[32][33];
  int c0 = blockIdx.x * 32, r0 = blockIdx.y * 32;
  int tx = threadIdx.x, ty = threadIdx.y;
#pragma unroll
  for (int i = 0; i < 32; i += 8)
    tile[ty + i][tx] = in[(size_t)(r0 + ty + i) * C + c0 + tx];
  __syncthreads();
#pragma unroll
  for (int i = 0; i < 32; i += 8)
    out[(size_t)(c0 + ty + i) * R + r0 + tx] = (half_t)tile[tx][ty + i];
}

// ---- one-time xh = x @ h_W + h_b  (fp16 out, h_b folded in)
__global__ __launch_bounds__(512, 2) void xh_kernel(
    const float* __restrict__ x, const half_t* __restrict__ hW_T,
    const float* __restrict__ h_b, half_t* __restrict__ xh_g) {
  extern __shared__ half_t sx[];
  const int tid = threadIdx.x;
  const int w = tid >> 6, l = tid & 63, q = l >> 4, c16 = l & 15;
  const int row0 = blockIdx.x * MT;
  for (int it = tid; it < MT * IN_DIM / 4; it += 512) {
    int r = it >> 8;
    int c = (it & 255) * 4;
    float4_ v = *(const float4_*)(x + (size_t)(row0 + r) * IN_DIM + c);
    half4v hv;
    hv[0] = (half_t)v[0]; hv[1] = (half_t)v[1]; hv[2] = (half_t)v[2]; hv[3] = (half_t)v[3];
    *(half4v*)(sx + r * XPITCH + c) = hv;
  }
  __syncthreads();
  const int n0 = w * 64;
  float4_ acc[4][2];
  const half_t* bbase = hW_T + (size_t)(n0 + c16) * IN_DIM + q * 8;
  stage_gemm<4, IN_DIM, XPITCH>(bbase, [](int nb) { return nb * 16 * IN_DIM; }, sx, q, c16, acc);
#pragma unroll
  for (int nb = 0; nb < 4; ++nb)
#pragma unroll
    for (int mb = 0; mb < 2; ++mb)
#pragma unroll
      for (int r = 0; r < 4; ++r) {
        int row = mb * 16 + q * 4 + r;
        int col = n0 + nb * 16 + c16;
        xh_g[(size_t)(row0 + row) * UNITS + col] = (half_t)(acc[nb][mb][r] + h_b[col]);
      }
}

// ---- the persistent scan kernel
__global__ __launch_bounds__(512, 2) void lstm_main(
    const half_t* __restrict__ xh_g, const half_t* __restrict__ hU_T,
    const half_t* __restrict__ W4_T, const half_t* __restrict__ tW_T,
    const half_t* __restrict__ yW_T,
    const float* __restrict__ f_b, const float* __restrict__ i_b,
    const float* __restrict__ c_b, const float* __restrict__ o_b,
    const float* __restrict__ t_b, const float* __restrict__ y_b,
    const float* __restrict__ h0, float* __restrict__ out) {
  extern __shared__ half_t smem[];
  half_t* s_state = smem;                 // h_prev / h1 (persistent)
  half_t* s_xh    = smem + MT * PITCH;    // xh (persistent, includes h_b)
  half_t* s_a     = smem + 2 * MT * PITCH;// h, then t
  half_t* s_b     = smem + 3 * MT * PITCH;// o*h1

  const int tid = threadIdx.x;
  const int w = tid >> 6, l = tid & 63, q = l >> 4, c16 = l & 15;
  const int row0 = blockIdx.x * MT;

  for (int it = tid; it < MT * UNITS / 8; it += 512) {
    int r = it >> 6;
    int c = (it & 63) * 8;
    *(half8*)(s_xh + r * PITCH + c) = *(const half8*)(xh_g + (size_t)(row0 + r) * UNITS + c);
  }
  for (int it = tid; it < MT * UNITS; it += 512) {
    int r = it >> 9;
    int c = it & (UNITS - 1);
    s_state[r * PITCH + c] = (half_t)h0[c];
  }

  const int n0 = w * 64;   // wave's 64-col slice for 512-wide stages
  const int n0y = w * 32;  // wave's 32-col slice for y (256-wide)
  float fb[4], ib[4], cb[4], ob[4], tb[4], yb[2];
#pragma unroll
  for (int nb = 0; nb < 4; ++nb) {
    int col = n0 + nb * 16 + c16;
    fb[nb] = f_b[col]; ib[nb] = i_b[col]; cb[nb] = c_b[col]; ob[nb] = o_b[col];
    tb[nb] = t_b[col];
  }
#pragma unroll
  for (int nb = 0; nb < 2; ++nb) yb[nb] = y_b[n0y + nb * 16 + c16];

  __syncthreads();

  for (int s = 0; s < DEPTH; ++s) {
    // stage 1: h = tanh(xh + state @ h_U)  -> s_a
    {
      float4_ acc[4][2];
      const half_t* bbase = hU_T + (size_t)(n0 + c16) * UNITS + q * 8;
      stage_gemm<4, UNITS, PITCH>(bbase, [](int nb) { return nb * 16 * UNITS; }, s_state, q, c16, acc);
#pragma unroll
      for (int nb = 0; nb < 4; ++nb)
#pragma unroll
        for (int mb = 0; mb < 2; ++mb)
#pragma unroll
          for (int r = 0; r < 4; ++r) {
            int row = mb * 16 + q * 4 + r;
            int col = n0 + nb * 16 + c16;
            float v = (float)s_xh[row * PITCH + col] + acc[nb][mb][r];
            s_a[row * PITCH + col] = (half_t)fast_tanh(v);
          }
    }
    __syncthreads();
    // stage 2: f,i,c,o = act(h @ W4); h1 = state*f + c*i; state = h1; s_b = o*h1
    {
      float4_ acc[16][2];  // [mat*4 + nb][mb]
      const half_t* bbase = W4_T + (size_t)(n0 + c16) * UNITS + q * 8;
      stage_gemm<16, UNITS, PITCH>(
          bbase, [](int nb) { return ((nb >> 2) * 512 + (nb & 3) * 16) * UNITS; },
          s_a, q, c16, acc);
#pragma unroll
      for (int nb = 0; nb < 4; ++nb)
#pragma unroll
        for (int mb = 0; mb < 2; ++mb)
#pragma unroll
          for (int r = 0; r < 4; ++r) {
            int row = mb * 16 + q * 4 + r;
            int col = n0 + nb * 16 + c16;
            float gf = fast_sigmoid(acc[0 * 4 + nb][mb][r] + fb[nb]);
            float gi = fast_sigmoid(acc[1 * 4 + nb][mb][r] + ib[nb]);
            float gc = fast_tanh   (acc[2 * 4 + nb][mb][r] + cb[nb]);
            float go = fast_sigmoid(acc[3 * 4 + nb][mb][r] + ob[nb]);
            float hp = (float)s_state[row * PITCH + col];
            float h1 = hp * gf + gc * gi;
            s_state[row * PITCH + col] = (half_t)h1;
            s_b[row * PITCH + col] = (half_t)(go * h1);
          }
    }
    __syncthreads();
    // stage 3: t = tanh((o*h1) @ t_W + t_b) -> s_a
    {
      float4_ acc[4][2];
      const half_t* bbase = tW_T + (size_t)(n0 + c16) * UNITS + q * 8;
      stage_gemm<4, UNITS, PITCH>(bbase, [](int nb) { return nb * 16 * UNITS; }, s_b, q, c16, acc);
#pragma unroll
      for (int nb = 0; nb < 4; ++nb)
#pragma unroll
        for (int mb = 0; mb < 2; ++mb)
#pragma unroll
          for (int r = 0; r < 4; ++r) {
            int row = mb * 16 + q * 4 + r;
            int col = n0 + nb * 16 + c16;
            s_a[row * PITCH + col] = (half_t)fast_tanh(acc[nb][mb][r] + tb[nb]);
          }
    }
    __syncthreads();
    // stage 4: y = tanh(t @ y_W + y_b) -> out[n][s][k]
    {
      float4_ acc[2][2];
      const half_t* bbase = yW_T + (size_t)(n0y + c16) * UNITS + q * 8;
      stage_gemm<2, UNITS, PITCH>(bbase, [](int nb) { return nb * 16 * UNITS; }, s_a, q, c16, acc);
#pragma unroll
      for (int nb = 0; nb < 2; ++nb)
#pragma unroll
        for (int mb = 0; mb < 2; ++mb)
#pragma unroll
          for (int r = 0; r < 4; ++r) {
            int row = mb * 16 + q * 4 + r;
            int col = n0y + nb * 16 + c16;
            out[((size_t)(row0 + row) * DEPTH + s) * ZK + col] = fast_tanh(acc[nb][mb][r] + yb[nb]);
          }
    }
    __syncthreads();
  }
}

extern "C" void kernel_launch(void* const* d_in, const int* in_sizes, int n_in,
                              void* d_out, int out_size, void* d_ws, size_t ws_size,
                              hipStream_t stream) {
  (void)in_sizes; (void)n_in; (void)out_size; (void)ws_size;
  const float* x   = (const float*)d_in[0];
  const float* h_W = (const float*)d_in[1];
  const float* h_U = (const float*)d_in[2];
  const float* h_b = (const float*)d_in[3];
  const float* f_W = (const float*)d_in[4];
  const float* f_b = (const float*)d_in[5];
  const float* i_W = (const float*)d_in[6];
  const float* i_b = (const float*)d_in[7];
  const float* c_W = (const float*)d_in[8];
  const float* c_b = (const float*)d_in[9];
  const float* o_W = (const float*)d_in[10];
  const float* o_b = (const float*)d_in[11];
  const float* t_W = (const float*)d_in[12];
  const float* t_b = (const float*)d_in[13];
  const float* y_W = (const float*)d_in[14];
  const float* y_b = (const float*)d_in[15];
  const float* h0  = (const float*)d_in[16];
  float* out = (float*)d_out;

  half_t* ws   = (half_t*)d_ws;          // ~12.9 MB of fp16 scratch
  half_t* hW_T = ws;                                   // [512][1024]
  half_t* hU_T = hW_T + (size_t)UNITS * IN_DIM;        // [512][512]
  half_t* W4_T = hU_T + (size_t)UNITS * UNITS;         // [2048][512] f,i,c,o
  half_t* tW_T = W4_T + (size_t)4 * UNITS * UNITS;     // [512][512]
  half_t* yW_T = tW_T + (size_t)UNITS * UNITS;         // [256][512]
  half_t* xh_g = yW_T + (size_t)ZK * UNITS;            // [8192][512]

  hipFuncSetAttribute((const void*)xh_kernel, hipFuncAttributeMaxDynamicSharedMemorySize,
                      MT * XPITCH * 2);
  hipFuncSetAttribute((const void*)lstm_main, hipFuncAttributeMaxDynamicSharedMemorySize,
                      4 * MT * PITCH * 2);

  dim3 tb(32, 8);
  hipLaunchKernelGGL(transpose_convert, dim3(UNITS / 32, IN_DIM / 32), tb, 0, stream,
                     h_W, hW_T, IN_DIM, UNITS);
  hipLaunchKernelGGL(transpose_convert, dim3(UNITS / 32, UNITS / 32), tb, 0, stream,
                     h_U, hU_T, UNITS, UNITS);
  hipLaunchKernelGGL(transpose_convert, dim3(UNITS / 32, UNITS / 32), tb, 0, stream,
                     f_W, W4_T + 0 * (size_t)UNITS * UNITS, UNITS, UNITS);
  hipLaunchKernelGGL(transpose_convert, dim3(UNITS / 32, UNITS / 32), tb, 0, stream,
                     i_W, W4_T + 1 * (size_t)UNITS * UNITS, UNITS, UNITS);
  hipLaunchKernelGGL(transpose_convert, dim3(UNITS / 32, UNITS / 32), tb, 0, stream,
                     c_W, W4_T + 2 * (size_t)UNITS * UNITS, UNITS, UNITS);
  hipLaunchKernelGGL(transpose_convert, dim3(UNITS / 32, UNITS / 32), tb, 0, stream,
                     o_W, W4_T + 3 * (size_t)UNITS * UNITS, UNITS, UNITS);
  hipLaunchKernelGGL(transpose_convert, dim3(UNITS / 32, UNITS / 32), tb, 0, stream,
                     t_W, tW_T, UNITS, UNITS);
  hipLaunchKernelGGL(transpose_convert, dim3(ZK / 32, UNITS / 32), tb, 0, stream,
                     y_W, yW_T, UNITS, ZK);
  hipLaunchKernelGGL(xh_kernel, dim3(NROWS / MT), dim3(512), MT * XPITCH * 2, stream,
                     x, hW_T, h_b, xh_g);
  hipLaunchKernelGGL(lstm_main, dim3(NROWS / MT), dim3(512), 4 * MT * PITCH * 2, stream,
                     xh_g, hU_T, W4_T, tW_T, yW_T, f_b, i_b, c_b, o_b, t_b, y_b, h0, out);
}

// Round 2
// 4401.008 us; speedup vs baseline: 1.6500x; 1.6500x over previous
//
#include <hip/hip_runtime.h>

// EncoderLSTMContinuous v2: MT=64 rows/WG (128 WGs), 2 LDS buffers, state in
// registers, operand-swapped MFMA (weights=A, acts=B) so D gives 4 consecutive
// cols per reg quad -> vectorized epilogues. nt stores for out to stop L2
// weight eviction (round-1 failure mode: FETCH_SIZE 14.2GB from thrash).

typedef _Float16 half_t;
typedef _Float16 half8 __attribute__((ext_vector_type(8)));
typedef _Float16 half4v __attribute__((ext_vector_type(4)));
typedef float float4_ __attribute__((ext_vector_type(4)));

#define UNITS 512
#define IN_DIM 1024
#define NROWS 8192
#define DEPTH 32
#define ZK 256
#define MT 64
#define PITCH (UNITS + 8)    // 520 halves
#define XPITCH (IN_DIM + 8)

__device__ inline float4_ mfma16(half8 a, half8 b, float4_ c) {
  // D[m][n]: m=(lane>>4)*4+reg, n=lane&15. A[m=lane&15][k=(lane>>4)*8+j], B[k][n=lane&15].
  return __builtin_amdgcn_mfma_f32_16x16x32_f16(a, b, c, 0, 0, 0);
}
__device__ inline float fast_sigmoid(float x) {
  return __builtin_amdgcn_rcpf(1.0f + __builtin_amdgcn_exp2f(-1.4426950408889634f * x));
}
__device__ inline float fast_tanh(float x) {
  return 2.0f * __builtin_amdgcn_rcpf(1.0f + __builtin_amdgcn_exp2f(-2.8853900817779268f * x)) - 1.0f;
}

// D[wcol_block NM x 16][actrow 64] += W_T rows * act rows.
// wbase = W_T + (colbase + c16)*UNITS + q*8 ; abase = buf + c16*PITCH + q*8.
// acc[i][rb]: reg r -> wcol = colbase + blk(i)*16 + q*4 + r ; lane c16 -> actrow rb*16+c16.
template<int NM, class OffF>
__device__ inline void sweepW(const half_t* __restrict__ wbase, OffF off,
                              const half_t* __restrict__ abase,
                              float4_ (&acc)[NM][4]) {
#pragma unroll
  for (int i = 0; i < NM; ++i)
#pragma unroll
    for (int rb = 0; rb < 4; ++rb) acc[i][rb] = {0.f, 0.f, 0.f, 0.f};
  for (int k0 = 0; k0 < UNITS; k0 += 64) {
    half8 a0[4], a1[4];
#pragma unroll
    for (int rb = 0; rb < 4; ++rb) {
      a0[rb] = *(const half8*)(abase + rb * 16 * PITCH + k0);
      a1[rb] = *(const half8*)(abase + rb * 16 * PITCH + k0 + 32);
    }
#pragma unroll
    for (int i = 0; i < NM; ++i) {
      const half_t* wp = wbase + off(i) + k0;
      half8 w0 = *(const half8*)(wp);
      half8 w1 = *(const half8*)(wp + 32);
#pragma unroll
      for (int rb = 0; rb < 4; ++rb) {
        acc[i][rb] = mfma16(w0, a0[rb], acc[i][rb]);
        acc[i][rb] = mfma16(w1, a1[rb], acc[i][rb]);
      }
    }
  }
}

// ---- old-orientation helper kept for xh_kernel (acts=A, weights=B)
template<int NB, int K, int AP, class OffF>
__device__ inline void stage_gemm(const half_t* __restrict__ bbase, OffF off,
                                  const half_t* __restrict__ A, int q, int c16,
                                  float4_ (&acc)[NB][2]) {
#pragma unroll
  for (int nb = 0; nb < NB; ++nb) {
    acc[nb][0] = {0.f, 0.f, 0.f, 0.f};
    acc[nb][1] = {0.f, 0.f, 0.f, 0.f};
  }
  for (int k0 = 0; k0 < K; k0 += 64) {
    const half_t* ap = A + c16 * AP + k0 + q * 8;
    half8 a00 = *(const half8*)(ap);
    half8 a01 = *(const half8*)(ap + 32);
    half8 a10 = *(const half8*)(ap + 16 * AP);
    half8 a11 = *(const half8*)(ap + 16 * AP + 32);
#pragma unroll
    for (int nb = 0; nb < NB; ++nb) {
      const half_t* bp = bbase + off(nb) + k0;
      half8 b0 = *(const half8*)(bp);
      half8 b1 = *(const half8*)(bp + 32);
      acc[nb][0] = mfma16(a00, b0, acc[nb][0]);
      acc[nb][0] = mfma16(a01, b1, acc[nb][0]);
      acc[nb][1] = mfma16(a10, b0, acc[nb][1]);
      acc[nb][1] = mfma16(a11, b1, acc[nb][1]);
    }
  }
}

// ---- prep: fp32 [R][C] -> fp16 [C][R] tiled transpose-convert
__global__ void transpose_convert(const float* __restrict__ in, half_t* __restrict__ out,
                                  int R, int C) {
  __shared__ float tile[32][33];
  int c0 = blockIdx.x * 32, r0 = blockIdx.y * 32;
  int tx = threadIdx.x, ty = threadIdx.y;
#pragma unroll
  for (int i = 0; i < 32; i += 8)
    tile[ty + i][tx] = in[(size_t)(r0 + ty + i) * C + c0 + tx];
  __syncthreads();
#pragma unroll
  for (int i = 0; i < 32; i += 8)
    out[(size_t)(c0 + ty + i) * R + r0 + tx] = (half_t)tile[tx][ty + i];
}

// ---- one-time xh = x @ h_W + h_b  (fp16 out, h_b folded in)
__global__ __launch_bounds__(512, 2) void xh_kernel(
    const float* __restrict__ x, const half_t* __restrict__ hW_T,
    const float* __restrict__ h_b, half_t* __restrict__ xh_g) {
  extern __shared__ half_t sx[];
  const int tid = threadIdx.x;
  const int w = tid >> 6, l = tid & 63, q = l >> 4, c16 = l & 15;
  const int row0 = blockIdx.x * 32;
  for (int it = tid; it < 32 * IN_DIM / 4; it += 512) {
    int r = it >> 8;
    int c = (it & 255) * 4;
    float4_ v = __builtin_nontemporal_load((const float4_*)(x + (size_t)(row0 + r) * IN_DIM + c));
    half4v hv;
    hv[0] = (half_t)v[0]; hv[1] = (half_t)v[1]; hv[2] = (half_t)v[2]; hv[3] = (half_t)v[3];
    *(half4v*)(sx + r * XPITCH + c) = hv;
  }
  __syncthreads();
  const int n0 = w * 64;
  float4_ acc[4][2];
  const half_t* bbase = hW_T + (size_t)(n0 + c16) * IN_DIM + q * 8;
  stage_gemm<4, IN_DIM, XPITCH>(bbase, [](int nb) { return nb * 16 * IN_DIM; }, sx, q, c16, acc);
#pragma unroll
  for (int nb = 0; nb < 4; ++nb)
#pragma unroll
    for (int mb = 0; mb < 2; ++mb)
#pragma unroll
      for (int r = 0; r < 4; ++r) {
        int row = mb * 16 + q * 4 + r;
        int col = n0 + nb * 16 + c16;
        xh_g[(size_t)(row0 + row) * UNITS + col] = (half_t)(acc[nb][mb][r] + h_b[col]);
      }
}

// ---- the persistent scan kernel (MT=64, 8 waves)
__global__ __launch_bounds__(512, 2) void lstm_main(
    const half_t* __restrict__ xh_g, const half_t* __restrict__ hU_T,
    const half_t* __restrict__ W4_T, const half_t* __restrict__ tW_T,
    const half_t* __restrict__ yW_T,
    const float* __restrict__ f_b, const float* __restrict__ i_b,
    const float* __restrict__ c_b, const float* __restrict__ o_b,
    const float* __restrict__ t_b, const float* __restrict__ y_b,
    const float* __restrict__ h0, float* __restrict__ out) {
  extern __shared__ half_t smem[];
  half_t* bufA = smem;                 // state -> (o*h1) -> state
  half_t* bufB = smem + MT * PITCH;    // h -> t

  const int tid = threadIdx.x;
  const int w = tid >> 6, l = tid & 63, q = l >> 4, c16 = l & 15;
  const int row0 = blockIdx.x * MT;

  // init bufA = broadcast h0 (fp16)
  for (int it = tid; it < MT * UNITS / 8; it += 512) {
    int r = it >> 6;
    int c = (it & 63) * 8;
    float4_ v0 = *(const float4_*)(h0 + c);
    float4_ v1 = *(const float4_*)(h0 + c + 4);
    half8 hv;
#pragma unroll
    for (int j = 0; j < 4; ++j) { hv[j] = (half_t)v0[j]; hv[4 + j] = (half_t)v1[j]; }
    *(half8*)(bufA + r * PITCH + c) = hv;
  }
  // state registers: positions row=rb*16+c16, col=hh*256+w*32+cm*16+q*4+r
  half4v state_r[2][2][4];
#pragma unroll
  for (int hh = 0; hh < 2; ++hh)
#pragma unroll
    for (int cm = 0; cm < 2; ++cm) {
      int col0 = hh * 256 + w * 32 + cm * 16 + q * 4;
      float4_ v = *(const float4_*)(h0 + col0);
      half4v s4;
#pragma unroll
      for (int r = 0; r < 4; ++r) s4[r] = (half_t)v[r];
#pragma unroll
      for (int rb = 0; rb < 4; ++rb) state_r[hh][cm][rb] = s4;
    }
  __syncthreads();

  for (int s = 0; s < DEPTH; ++s) {
    // ---- stage 1: h = tanh(xh + state @ h_U) : read bufA -> write bufB
    {
      float4_ acc[4][4];
      const half_t* wb = hU_T + (size_t)(w * 64 + c16) * UNITS + q * 8;
      sweepW<4>(wb, [](int i) { return i * 16 * UNITS; }, bufA + c16 * PITCH + q * 8, acc);
#pragma unroll
      for (int cm = 0; cm < 4; ++cm) {
        int col0 = w * 64 + cm * 16 + q * 4;
#pragma unroll
        for (int rb = 0; rb < 4; ++rb) {
          int row = rb * 16 + c16;
          half4v xh4 = *(const half4v*)(xh_g + (size_t)(row0 + row) * UNITS + col0);
          half4v hv;
#pragma unroll
          for (int r = 0; r < 4; ++r) hv[r] = (half_t)fast_tanh(acc[cm][rb][r] + (float)xh4[r]);
          *(half4v*)(bufB + row * PITCH + col0) = hv;
        }
      }
    }
    __syncthreads();
    // ---- stage 2: gates from h (bufB); two column-half sweeps; write o*h1 -> bufA
#pragma unroll 1
    for (int hh = 0; hh < 2; ++hh) {
      float4_ acc[8][4];  // i = mat*2 + cm
      const int colbase = hh * 256 + w * 32;
      const half_t* wb = W4_T + (size_t)(colbase + c16) * UNITS + q * 8;
      sweepW<8>(wb, [](int i) { return (i >> 1) * (UNITS * UNITS) + (i & 1) * 16 * UNITS; },
                bufB + c16 * PITCH + q * 8, acc);
#pragma unroll
      for (int cm = 0; cm < 2; ++cm) {
        int col0 = colbase + cm * 16 + q * 4;
        float4_ fb4 = *(const float4_*)(f_b + col0);
        float4_ ib4 = *(const float4_*)(i_b + col0);
        float4_ cb4 = *(const float4_*)(c_b + col0);
        float4_ ob4 = *(const float4_*)(o_b + col0);
#pragma unroll
        for (int rb = 0; rb < 4; ++rb) {
          int row = rb * 16 + c16;
          half4v hp = state_r[hh][cm][rb];
          half4v h1v, sbv;
#pragma unroll
          for (int r = 0; r < 4; ++r) {
            float gf = fast_sigmoid(acc[0 * 2 + cm][rb][r] + fb4[r]);
            float gi = fast_sigmoid(acc[1 * 2 + cm][rb][r] + ib4[r]);
            float gc = fast_tanh   (acc[2 * 2 + cm][rb][r] + cb4[r]);
            float go = fast_sigmoid(acc[3 * 2 + cm][rb][r] + ob4[r]);
            float h1 = (float)hp[r] * gf + gc * gi;
            h1v[r] = (half_t)h1;
            sbv[r] = (half_t)(go * h1);
          }
          state_r[hh][cm][rb] = h1v;
          *(half4v*)(bufA + row * PITCH + col0) = sbv;
        }
      }
    }
    __syncthreads();
    // ---- stage 3: t = tanh((o*h1) @ t_W + t_b) : read bufA -> write bufB
    {
      float4_ acc[4][4];
      const half_t* wb = tW_T + (size_t)(w * 64 + c16) * UNITS + q * 8;
      sweepW<4>(wb, [](int i) { return i * 16 * UNITS; }, bufA + c16 * PITCH + q * 8, acc);
#pragma unroll
      for (int cm = 0; cm < 4; ++cm) {
        int col0 = w * 64 + cm * 16 + q * 4;
        float4_ tb4 = *(const float4_*)(t_b + col0);
#pragma unroll
        for (int rb = 0; rb < 4; ++rb) {
          int row = rb * 16 + c16;
          half4v hv;
#pragma unroll
          for (int r = 0; r < 4; ++r) hv[r] = (half_t)fast_tanh(acc[cm][rb][r] + tb4[r]);
          *(half4v*)(bufB + row * PITCH + col0) = hv;
        }
      }
    }
    __syncthreads();
    // ---- stage 4: y = tanh(t @ y_W + y_b) -> nt-store out ; also state regs -> bufA
    {
      float4_ acc[2][4];
      const half_t* wb = yW_T + (size_t)(w * 32 + c16) * UNITS + q * 8;
      sweepW<2>(wb, [](int i) { return i * 16 * UNITS; }, bufB + c16 * PITCH + q * 8, acc);
#pragma unroll
      for (int cm = 0; cm < 2; ++cm) {
        int col0 = w * 32 + cm * 16 + q * 4;
        float4_ yb4 = *(const float4_*)(y_b + col0);
#pragma unroll
        for (int rb = 0; rb < 4; ++rb) {
          int row = rb * 16 + c16;
          float4_ yv;
#pragma unroll
          for (int r = 0; r < 4; ++r) yv[r] = fast_tanh(acc[cm][rb][r] + yb4[r]);
          __builtin_nontemporal_store(yv,
              (float4_*)(out + ((size_t)(row0 + row) * DEPTH + s) * ZK + col0));
        }
      }
      // restore bufA = state for next step's stage 1
#pragma unroll
      for (int hh = 0; hh < 2; ++hh)
#pragma unroll
        for (int cm = 0; cm < 2; ++cm) {
          int col0 = hh * 256 + w * 32 + cm * 16 + q * 4;
#pragma unroll
          for (int rb = 0; rb < 4; ++rb)
            *(half4v*)(bufA + (rb * 16 + c16) * PITCH + col0) = state_r[hh][cm][rb];
        }
    }
    __syncthreads();
  }
}

extern "C" void kernel_launch(void* const* d_in, const int* in_sizes, int n_in,
                              void* d_out, int out_size, void* d_ws, size_t ws_size,
                              hipStream_t stream) {
  (void)in_sizes; (void)n_in; (void)out_size; (void)ws_size;
  const float* x   = (const float*)d_in[0];
  const float* h_W = (const float*)d_in[1];
  const float* h_U = (const float*)d_in[2];
  const float* h_b = (const float*)d_in[3];
  const float* f_W = (const float*)d_in[4];
  const float* f_b = (const float*)d_in[5];
  const float* i_W = (const float*)d_in[6];
  const float* i_b = (const float*)d_in[7];
  const float* c_W = (const float*)d_in[8];
  const float* c_b = (const float*)d_in[9];
  const float* o_W = (const float*)d_in[10];
  const float* o_b = (const float*)d_in[11];
  const float* t_W = (const float*)d_in[12];
  const float* t_b = (const float*)d_in[13];
  const float* y_W = (const float*)d_in[14];
  const float* y_b = (const float*)d_in[15];
  const float* h0  = (const float*)d_in[16];
  float* out = (float*)d_out;

  half_t* ws   = (half_t*)d_ws;
  half_t* hW_T = ws;                                   // [512][1024]
  half_t* hU_T = hW_T + (size_t)UNITS * IN_DIM;        // [512][512]
  half_t* W4_T = hU_T + (size_t)UNITS * UNITS;         // [2048][512] f,i,c,o
  half_t* tW_T = W4_T + (size_t)4 * UNITS * UNITS;     // [512][512]
  half_t* yW_T = tW_T + (size_t)UNITS * UNITS;         // [256][512]
  half_t* xh_g = yW_T + (size_t)ZK * UNITS;            // [8192][512]

  hipFuncSetAttribute((const void*)xh_kernel, hipFuncAttributeMaxDynamicSharedMemorySize,
                      32 * XPITCH * 2);
  hipFuncSetAttribute((const void*)lstm_main, hipFuncAttributeMaxDynamicSharedMemorySize,
                      2 * MT * PITCH * 2);

  dim3 tb(32, 8);
  hipLaunchKernelGGL(transpose_convert, dim3(UNITS / 32, IN_DIM / 32), tb, 0, stream,
                     h_W, hW_T, IN_DIM, UNITS);
  hipLaunchKernelGGL(transpose_convert, dim3(UNITS / 32, UNITS / 32), tb, 0, stream,
                     h_U, hU_T, UNITS, UNITS);
  hipLaunchKernelGGL(transpose_convert, dim3(UNITS / 32, UNITS / 32), tb, 0, stream,
                     f_W, W4_T + 0 * (size_t)UNITS * UNITS, UNITS, UNITS);
  hipLaunchKernelGGL(transpose_convert, dim3(UNITS / 32, UNITS / 32), tb, 0, stream,
                     i_W, W4_T + 1 * (size_t)UNITS * UNITS, UNITS, UNITS);
  hipLaunchKernelGGL(transpose_convert, dim3(UNITS / 32, UNITS / 32), tb, 0, stream,
                     c_W, W4_T + 2 * (size_t)UNITS * UNITS, UNITS, UNITS);
  hipLaunchKernelGGL(transpose_convert, dim3(UNITS / 32, UNITS / 32), tb, 0, stream,
                     o_W, W4_T + 3 * (size_t)UNITS * UNITS, UNITS, UNITS);
  hipLaunchKernelGGL(transpose_convert, dim3(UNITS / 32, UNITS / 32), tb, 0, stream,
                     t_W, tW_T, UNITS, UNITS);
  hipLaunchKernelGGL(transpose_convert, dim3(ZK / 32, UNITS / 32), tb, 0, stream,
                     y_W, yW_T, UNITS, ZK);
  hipLaunchKernelGGL(xh_kernel, dim3(NROWS / 32), dim3(512), 32 * XPITCH * 2, stream,
                     x, hW_T, h_b, xh_g);
  hipLaunchKernelGGL(lstm_main, dim3(NROWS / MT), dim3(512), 2 * MT * PITCH * 2, stream,
                     xh_g, hU_T, W4_T, tW_T, yW_T, f_b, i_b, c_b, o_b, t_b, y_b, h0, out);
}

// Round 3
// 4360.041 us; speedup vs baseline: 1.6655x; 1.0094x over previous
//
#include <hip/hip_runtime.h>

// EncoderLSTMContinuous v3: back to MT=32 / 256 WGs (1 per CU, all CUs busy —
// round-2 failure: 128 WGs left half the machine idle), keeping v2's structure
// (weights-as-A MFMA, state in regs, nt out-stores). New: register
// double-buffer prefetch of the L2 weight stream inside sweepW, xh + biases
// cached in LDS. Design floor: per-CU L2 weight stream 3.4MB/step @ ~56B/cyc
// => ~25us/step => ~800us.

typedef _Float16 half_t;
typedef _Float16 half8 __attribute__((ext_vector_type(8)));
typedef _Float16 half4v __attribute__((ext_vector_type(4)));
typedef float float4_ __attribute__((ext_vector_type(4)));

#define UNITS 512
#define IN_DIM 1024
#define NROWS 8192
#define DEPTH 32
#define ZK 256
#define MT 32
#define PITCH (UNITS + 8)    // 520 halves; 260 dwords ≡ 4 mod 32 -> 2-way (free) on b128
#define XPITCH (IN_DIM + 8)

__device__ inline float4_ mfma16(half8 a, half8 b, float4_ c) {
  // D[m][n]: m=(lane>>4)*4+reg, n=lane&15. A[m=lane&15][k=(lane>>4)*8+j], B[k][n=lane&15].
  return __builtin_amdgcn_mfma_f32_16x16x32_f16(a, b, c, 0, 0, 0);
}
__device__ inline float fast_sigmoid(float x) {
  return __builtin_amdgcn_rcpf(1.0f + __builtin_amdgcn_exp2f(-1.4426950408889634f * x));
}
__device__ inline float fast_tanh(float x) {
  return 2.0f * __builtin_amdgcn_rcpf(1.0f + __builtin_amdgcn_exp2f(-2.8853900817779268f * x)) - 1.0f;
}

// acc[i][rb]: reg r -> wcol = colbase + blk(i)*16 + q*4 + r ; lane c16 -> actrow rb*16+c16.
// wbase = W_T + (colbase + c16)*UNITS + q*8 ; abase = buf + c16*PITCH + q*8.
// Register double-buffer: iteration kk prefetches kk+1's weights before MFMAs.
template<int NM, class OffF>
__device__ inline void sweepW(const half_t* __restrict__ wbase, OffF off,
                              const half_t* __restrict__ abase,
                              float4_ (&acc)[NM][2]) {
#pragma unroll
  for (int i = 0; i < NM; ++i) {
    acc[i][0] = {0.f, 0.f, 0.f, 0.f};
    acc[i][1] = {0.f, 0.f, 0.f, 0.f};
  }
  half8 w0[2][NM], w1[2][NM];
#pragma unroll
  for (int i = 0; i < NM; ++i) {
    w0[0][i] = *(const half8*)(wbase + off(i));
    w1[0][i] = *(const half8*)(wbase + off(i) + 32);
  }
#pragma unroll
  for (int kk = 0; kk < 8; ++kk) {
    const int cur = kk & 1, nxt = cur ^ 1;
    const int knext = ((kk + 1) & 7) * 64;  // wraps to 0 on last iter (L1-hot, harmless)
#pragma unroll
    for (int i = 0; i < NM; ++i) {
      w0[nxt][i] = *(const half8*)(wbase + off(i) + knext);
      w1[nxt][i] = *(const half8*)(wbase + off(i) + knext + 32);
    }
    const int k0 = kk * 64;
    half8 a00 = *(const half8*)(abase + k0);
    half8 a01 = *(const half8*)(abase + k0 + 32);
    half8 a10 = *(const half8*)(abase + 16 * PITCH + k0);
    half8 a11 = *(const half8*)(abase + 16 * PITCH + k0 + 32);
#pragma unroll
    for (int i = 0; i < NM; ++i) {
      acc[i][0] = mfma16(w0[cur][i], a00, acc[i][0]);
      acc[i][0] = mfma16(w1[cur][i], a01, acc[i][0]);
      acc[i][1] = mfma16(w0[cur][i], a10, acc[i][1]);
      acc[i][1] = mfma16(w1[cur][i], a11, acc[i][1]);
    }
  }
}

// ---- old-orientation helper for xh_kernel (acts=A, weights=B)
template<int NB, int K, int AP, class OffF>
__device__ inline void stage_gemm(const half_t* __restrict__ bbase, OffF off,
                                  const half_t* __restrict__ A, int q, int c16,
                                  float4_ (&acc)[NB][2]) {
#pragma unroll
  for (int nb = 0; nb < NB; ++nb) {
    acc[nb][0] = {0.f, 0.f, 0.f, 0.f};
    acc[nb][1] = {0.f, 0.f, 0.f, 0.f};
  }
  for (int k0 = 0; k0 < K; k0 += 64) {
    const half_t* ap = A + c16 * AP + k0 + q * 8;
    half8 a00 = *(const half8*)(ap);
    half8 a01 = *(const half8*)(ap + 32);
    half8 a10 = *(const half8*)(ap + 16 * AP);
    half8 a11 = *(const half8*)(ap + 16 * AP + 32);
#pragma unroll
    for (int nb = 0; nb < NB; ++nb) {
      const half_t* bp = bbase + off(nb) + k0;
      half8 b0 = *(const half8*)(bp);
      half8 b1 = *(const half8*)(bp + 32);
      acc[nb][0] = mfma16(a00, b0, acc[nb][0]);
      acc[nb][0] = mfma16(a01, b1, acc[nb][0]);
      acc[nb][1] = mfma16(a10, b0, acc[nb][1]);
      acc[nb][1] = mfma16(a11, b1, acc[nb][1]);
    }
  }
}

// ---- prep: fp32 [R][C] -> fp16 [C][R] tiled transpose-convert
__global__ void transpose_convert(const float* __restrict__ in, half_t* __restrict__ out,
                                  int R, int C) {
  __shared__ float tile[32][33];
  int c0 = blockIdx.x * 32, r0 = blockIdx.y * 32;
  int tx = threadIdx.x, ty = threadIdx.y;
#pragma unroll
  for (int i = 0; i < 32; i += 8)
    tile[ty + i][tx] = in[(size_t)(r0 + ty + i) * C + c0 + tx];
  __syncthreads();
#pragma unroll
  for (int i = 0; i < 32; i += 8)
    out[(size_t)(c0 + ty + i) * R + r0 + tx] = (half_t)tile[tx][ty + i];
}

// ---- one-time xh = x @ h_W + h_b  (fp16 out, h_b folded in)
__global__ __launch_bounds__(512, 2) void xh_kernel(
    const float* __restrict__ x, const half_t* __restrict__ hW_T,
    const float* __restrict__ h_b, half_t* __restrict__ xh_g) {
  extern __shared__ half_t sx[];
  const int tid = threadIdx.x;
  const int w = tid >> 6, l = tid & 63, q = l >> 4, c16 = l & 15;
  const int row0 = blockIdx.x * 32;
  for (int it = tid; it < 32 * IN_DIM / 4; it += 512) {
    int r = it >> 8;
    int c = (it & 255) * 4;
    float4_ v = __builtin_nontemporal_load((const float4_*)(x + (size_t)(row0 + r) * IN_DIM + c));
    half4v hv;
    hv[0] = (half_t)v[0]; hv[1] = (half_t)v[1]; hv[2] = (half_t)v[2]; hv[3] = (half_t)v[3];
    *(half4v*)(sx + r * XPITCH + c) = hv;
  }
  __syncthreads();
  const int n0 = w * 64;
  float4_ acc[4][2];
  const half_t* bbase = hW_T + (size_t)(n0 + c16) * IN_DIM + q * 8;
  stage_gemm<4, IN_DIM, XPITCH>(bbase, [](int nb) { return nb * 16 * IN_DIM; }, sx, q, c16, acc);
#pragma unroll
  for (int nb = 0; nb < 4; ++nb)
#pragma unroll
    for (int mb = 0; mb < 2; ++mb)
#pragma unroll
      for (int r = 0; r < 4; ++r) {
        int row = mb * 16 + q * 4 + r;
        int col = n0 + nb * 16 + c16;
        xh_g[(size_t)(row0 + row) * UNITS + col] = (half_t)(acc[nb][mb][r] + h_b[col]);
      }
}

// ---- the persistent scan kernel (MT=32, 256 WGs, 8 waves each)
__global__ __launch_bounds__(512, 2) void lstm_main(
    const half_t* __restrict__ xh_g, const half_t* __restrict__ hU_T,
    const half_t* __restrict__ W4_T, const half_t* __restrict__ tW_T,
    const half_t* __restrict__ yW_T,
    const float* __restrict__ f_b, const float* __restrict__ i_b,
    const float* __restrict__ c_b, const float* __restrict__ o_b,
    const float* __restrict__ t_b, const float* __restrict__ y_b,
    const float* __restrict__ h0, float* __restrict__ out) {
  extern __shared__ half_t smem[];
  half_t* bufA = smem;                 // state -> (o*h1) -> state
  half_t* bufB = smem + MT * PITCH;    // h -> t
  half_t* s_xh = smem + 2 * MT * PITCH;                 // xh, persistent all 32 steps
  float* s_bias = (float*)(smem + 3 * MT * PITCH);      // f,i,c,o,t (512 ea) + y (256)
  float* s_fb = s_bias;
  float* s_ib = s_bias + 512;
  float* s_cb = s_bias + 1024;
  float* s_ob = s_bias + 1536;
  float* s_tb = s_bias + 2048;
  float* s_yb = s_bias + 2560;

  const int tid = threadIdx.x;
  const int w = tid >> 6, l = tid & 63, q = l >> 4, c16 = l & 15;
  const int row0 = blockIdx.x * MT;

  // init bufA = broadcast h0 (fp16); s_xh from xh_g; biases
  for (int it = tid; it < MT * UNITS / 8; it += 512) {
    int r = it >> 6;
    int c = (it & 63) * 8;
    float4_ v0 = *(const float4_*)(h0 + c);
    float4_ v1 = *(const float4_*)(h0 + c + 4);
    half8 hv;
#pragma unroll
    for (int j = 0; j < 4; ++j) { hv[j] = (half_t)v0[j]; hv[4 + j] = (half_t)v1[j]; }
    *(half8*)(bufA + r * PITCH + c) = hv;
    *(half8*)(s_xh + r * PITCH + c) = *(const half8*)(xh_g + (size_t)(row0 + r) * UNITS + c);
  }
  for (int it = tid; it < 512; it += 512) {
    s_fb[it] = f_b[it]; s_ib[it] = i_b[it]; s_cb[it] = c_b[it]; s_ob[it] = o_b[it];
    s_tb[it] = t_b[it];
    if (it < 256) s_yb[it] = y_b[it];
  }
  // state registers: row = rb*16 + c16, col = hh*256 + w*32 + cm*16 + q*4 + r
  half4v state_r[2][2][2];
#pragma unroll
  for (int hh = 0; hh < 2; ++hh)
#pragma unroll
    for (int cm = 0; cm < 2; ++cm) {
      int col0 = hh * 256 + w * 32 + cm * 16 + q * 4;
      float4_ v = *(const float4_*)(h0 + col0);
      half4v s4;
#pragma unroll
      for (int r = 0; r < 4; ++r) s4[r] = (half_t)v[r];
#pragma unroll
      for (int rb = 0; rb < 2; ++rb) state_r[hh][cm][rb] = s4;
    }
  __syncthreads();

  const half_t* abase_off = (const half_t*)0 + c16 * PITCH + q * 8;  // reused pattern
  (void)abase_off;

  for (int s = 0; s < DEPTH; ++s) {
    // ---- stage 1: h = tanh(xh + state @ h_U) : read bufA -> write bufB
    {
      float4_ acc[4][2];
      const half_t* wb = hU_T + (size_t)(w * 64 + c16) * UNITS + q * 8;
      sweepW<4>(wb, [](int i) { return i * 16 * UNITS; }, bufA + c16 * PITCH + q * 8, acc);
#pragma unroll
      for (int cm = 0; cm < 4; ++cm) {
        int col0 = w * 64 + cm * 16 + q * 4;
#pragma unroll
        for (int rb = 0; rb < 2; ++rb) {
          int row = rb * 16 + c16;
          half4v xh4 = *(const half4v*)(s_xh + row * PITCH + col0);
          half4v hv;
#pragma unroll
          for (int r = 0; r < 4; ++r) hv[r] = (half_t)fast_tanh(acc[cm][rb][r] + (float)xh4[r]);
          *(half4v*)(bufB + row * PITCH + col0) = hv;
        }
      }
    }
    __syncthreads();
    // ---- stage 2: gates from h (bufB); two column-half sweeps; write o*h1 -> bufA
#pragma unroll 1
    for (int hh = 0; hh < 2; ++hh) {
      float4_ acc[8][2];  // i = mat*2 + cm
      const int colbase = hh * 256 + w * 32;
      const half_t* wb = W4_T + (size_t)(colbase + c16) * UNITS + q * 8;
      sweepW<8>(wb, [](int i) { return (i >> 1) * (UNITS * UNITS) + (i & 1) * 16 * UNITS; },
                bufB + c16 * PITCH + q * 8, acc);
#pragma unroll
      for (int cm = 0; cm < 2; ++cm) {
        int col0 = colbase + cm * 16 + q * 4;
        float4_ fb4 = *(const float4_*)(s_fb + col0);
        float4_ ib4 = *(const float4_*)(s_ib + col0);
        float4_ cb4 = *(const float4_*)(s_cb + col0);
        float4_ ob4 = *(const float4_*)(s_ob + col0);
#pragma unroll
        for (int rb = 0; rb < 2; ++rb) {
          int row = rb * 16 + c16;
          half4v hp = state_r[hh][cm][rb];
          half4v h1v, sbv;
#pragma unroll
          for (int r = 0; r < 4; ++r) {
            float gf = fast_sigmoid(acc[0 * 2 + cm][rb][r] + fb4[r]);
            float gi = fast_sigmoid(acc[1 * 2 + cm][rb][r] + ib4[r]);
            float gc = fast_tanh   (acc[2 * 2 + cm][rb][r] + cb4[r]);
            float go = fast_sigmoid(acc[3 * 2 + cm][rb][r] + ob4[r]);
            float h1 = (float)hp[r] * gf + gc * gi;
            h1v[r] = (half_t)h1;
            sbv[r] = (half_t)(go * h1);
          }
          state_r[hh][cm][rb] = h1v;
          *(half4v*)(bufA + row * PITCH + col0) = sbv;
        }
      }
    }
    __syncthreads();
    // ---- stage 3: t = tanh((o*h1) @ t_W + t_b) : read bufA -> write bufB
    {
      float4_ acc[4][2];
      const half_t* wb = tW_T + (size_t)(w * 64 + c16) * UNITS + q * 8;
      sweepW<4>(wb, [](int i) { return i * 16 * UNITS; }, bufA + c16 * PITCH + q * 8, acc);
#pragma unroll
      for (int cm = 0; cm < 4; ++cm) {
        int col0 = w * 64 + cm * 16 + q * 4;
        float4_ tb4 = *(const float4_*)(s_tb + col0);
#pragma unroll
        for (int rb = 0; rb < 2; ++rb) {
          int row = rb * 16 + c16;
          half4v hv;
#pragma unroll
          for (int r = 0; r < 4; ++r) hv[r] = (half_t)fast_tanh(acc[cm][rb][r] + tb4[r]);
          *(half4v*)(bufB + row * PITCH + col0) = hv;
        }
      }
    }
    __syncthreads();
    // ---- stage 4: y = tanh(t @ y_W + y_b) -> nt-store out ; state regs -> bufA
    {
      float4_ acc[2][2];
      const half_t* wb = yW_T + (size_t)(w * 32 + c16) * UNITS + q * 8;
      sweepW<2>(wb, [](int i) { return i * 16 * UNITS; }, bufB + c16 * PITCH + q * 8, acc);
#pragma unroll
      for (int cm = 0; cm < 2; ++cm) {
        int col0 = w * 32 + cm * 16 + q * 4;
        float4_ yb4 = *(const float4_*)(s_yb + col0);
#pragma unroll
        for (int rb = 0; rb < 2; ++rb) {
          int row = rb * 16 + c16;
          float4_ yv;
#pragma unroll
          for (int r = 0; r < 4; ++r) yv[r] = fast_tanh(acc[cm][rb][r] + yb4[r]);
          __builtin_nontemporal_store(yv,
              (float4_*)(out + ((size_t)(row0 + row) * DEPTH + s) * ZK + col0));
        }
      }
#pragma unroll
      for (int hh = 0; hh < 2; ++hh)
#pragma unroll
        for (int cm = 0; cm < 2; ++cm) {
          int col0 = hh * 256 + w * 32 + cm * 16 + q * 4;
#pragma unroll
          for (int rb = 0; rb < 2; ++rb)
            *(half4v*)(bufA + (rb * 16 + c16) * PITCH + col0) = state_r[hh][cm][rb];
        }
    }
    __syncthreads();
  }
}

extern "C" void kernel_launch(void* const* d_in, const int* in_sizes, int n_in,
                              void* d_out, int out_size, void* d_ws, size_t ws_size,
                              hipStream_t stream) {
  (void)in_sizes; (void)n_in; (void)out_size; (void)ws_size;
  const float* x   = (const float*)d_in[0];
  const float* h_W = (const float*)d_in[1];
  const float* h_U = (const float*)d_in[2];
  const float* h_b = (const float*)d_in[3];
  const float* f_W = (const float*)d_in[4];
  const float* f_b = (const float*)d_in[5];
  const float* i_W = (const float*)d_in[6];
  const float* i_b = (const float*)d_in[7];
  const float* c_W = (const float*)d_in[8];
  const float* c_b = (const float*)d_in[9];
  const float* o_W = (const float*)d_in[10];
  const float* o_b = (const float*)d_in[11];
  const float* t_W = (const float*)d_in[12];
  const float* t_b = (const float*)d_in[13];
  const float* y_W = (const float*)d_in[14];
  const float* y_b = (const float*)d_in[15];
  const float* h0  = (const float*)d_in[16];
  float* out = (float*)d_out;

  half_t* ws   = (half_t*)d_ws;
  half_t* hW_T = ws;                                   // [512][1024]
  half_t* hU_T = hW_T + (size_t)UNITS * IN_DIM;        // [512][512]
  half_t* W4_T = hU_T + (size_t)UNITS * UNITS;         // [2048][512] f,i,c,o
  half_t* tW_T = W4_T + (size_t)4 * UNITS * UNITS;     // [512][512]
  half_t* yW_T = tW_T + (size_t)UNITS * UNITS;         // [256][512]
  half_t* xh_g = yW_T + (size_t)ZK * UNITS;            // [8192][512]

  const int lds_main = 3 * MT * PITCH * 2 + 2816 * 4;  // bufA,bufB,s_xh + biases
  hipFuncSetAttribute((const void*)xh_kernel, hipFuncAttributeMaxDynamicSharedMemorySize,
                      32 * XPITCH * 2);
  hipFuncSetAttribute((const void*)lstm_main, hipFuncAttributeMaxDynamicSharedMemorySize,
                      lds_main);

  dim3 tb(32, 8);
  hipLaunchKernelGGL(transpose_convert, dim3(UNITS / 32, IN_DIM / 32), tb, 0, stream,
                     h_W, hW_T, IN_DIM, UNITS);
  hipLaunchKernelGGL(transpose_convert, dim3(UNITS / 32, UNITS / 32), tb, 0, stream,
                     h_U, hU_T, UNITS, UNITS);
  hipLaunchKernelGGL(transpose_convert, dim3(UNITS / 32, UNITS / 32), tb, 0, stream,
                     f_W, W4_T + 0 * (size_t)UNITS * UNITS, UNITS, UNITS);
  hipLaunchKernelGGL(transpose_convert, dim3(UNITS / 32, UNITS / 32), tb, 0, stream,
                     i_W, W4_T + 1 * (size_t)UNITS * UNITS, UNITS, UNITS);
  hipLaunchKernelGGL(transpose_convert, dim3(UNITS / 32, UNITS / 32), tb, 0, stream,
                     c_W, W4_T + 2 * (size_t)UNITS * UNITS, UNITS, UNITS);
  hipLaunchKernelGGL(transpose_convert, dim3(UNITS / 32, UNITS / 32), tb, 0, stream,
                     o_W, W4_T + 3 * (size_t)UNITS * UNITS, UNITS, UNITS);
  hipLaunchKernelGGL(transpose_convert, dim3(UNITS / 32, UNITS / 32), tb, 0, stream,
                     t_W, tW_T, UNITS, UNITS);
  hipLaunchKernelGGL(transpose_convert, dim3(ZK / 32, UNITS / 32), tb, 0, stream,
                     y_W, yW_T, UNITS, ZK);
  hipLaunchKernelGGL(xh_kernel, dim3(NROWS / 32), dim3(512), 32 * XPITCH * 2, stream,
                     x, hW_T, h_b, xh_g);
  hipLaunchKernelGGL(lstm_main, dim3(NROWS / MT), dim3(512), lds_main, stream,
                     xh_g, hU_T, W4_T, tW_T, yW_T, f_b, i_b, c_b, o_b, t_b, y_b, h0, out);
}